// Round 1
// baseline (330.456 us; speedup 1.0000x reference)
//
#include <hip/hip_runtime.h>
#include <cstdint>
#include <cstddef>

typedef _Float16 h8_t __attribute__((ext_vector_type(8)));
typedef _Float16 h4_t __attribute__((ext_vector_type(4)));
typedef float f32x4 __attribute__((ext_vector_type(4)));

#define MFMA_16x16x32_F16(a, b, c) __builtin_amdgcn_mfma_f32_16x16x32_f16(a, b, c, 0, 0, 0)

__device__ inline void gload_lds16(const void* g, void* l) {
  __builtin_amdgcn_global_load_lds((const __attribute__((address_space(1))) void*)g,
                                   (__attribute__((address_space(3))) void*)l, 16, 0, 0);
}

// ---------------- convert f32 -> f16 ----------------
__global__ void cvt_f16_kernel(const float* __restrict__ in, _Float16* __restrict__ out, int n4) {
  int i = blockIdx.x * 256 + threadIdx.x;
  if (i >= n4) return;
  float4 v = reinterpret_cast<const float4*>(in)[i];
  h4_t h;
  h[0] = (_Float16)v.x; h[1] = (_Float16)v.y; h[2] = (_Float16)v.z; h[3] = (_Float16)v.w;
  reinterpret_cast<h4_t*>(out)[i] = h;
}

// ---------------- transpose + convert: in[R][Cc] f32 -> out[Cc][R] f16 ----------------
__global__ void transpose_cvt_kernel(const float* __restrict__ in, _Float16* __restrict__ out,
                                     int R, int Cc) {
  __shared__ float tile[32][33];
  int tx = threadIdx.x & 31;
  int ty = threadIdx.x >> 5;  // 0..7
  int c0 = blockIdx.x * 32;
  int r0 = blockIdx.y * 32;
#pragma unroll
  for (int i = 0; i < 4; ++i)
    tile[ty + i * 8][tx] = in[(size_t)(r0 + ty + i * 8) * Cc + (c0 + tx)];
  __syncthreads();
#pragma unroll
  for (int i = 0; i < 4; ++i)
    out[(size_t)(c0 + ty + i * 8) * R + (r0 + tx)] = (_Float16)tile[tx][ty + i * 8];
}

// ---------------- GEMM  C[m][n] = sum_k A[m][k]*Bt[n][k] + bias[n] ----------------
// A: [M][1024] f16, Bt: [N][1024] f16. 128x128 tile, BK=32, 4 waves (2x2), 64x64/wave.
// EPI 0: route to Q (scaled 1/8), K as (BH,T,D) f16 and V transposed (BH,D,T) f16.
// EPI 1: plain fp32 output [M][N].
template <int EPI>
__global__ __launch_bounds__(256, 2) void gemm_bt_kernel(
    const _Float16* __restrict__ A, const _Float16* __restrict__ Bt,
    const float* __restrict__ bias, _Float16* __restrict__ outQ,
    _Float16* __restrict__ outK, _Float16* __restrict__ outV,
    float* __restrict__ outF, int NB) {
  __shared__ _Float16 Al[128 * 32];
  __shared__ _Float16 Bl[128 * 32];
  const int tid = threadIdx.x;
  const int lane = tid & 63;
  const int w = tid >> 6;
  const int bm = blockIdx.x / NB;
  const int bn = blockIdx.x % NB;
  const int wm = w & 1, wn = w >> 1;

  f32x4 acc[4][4] = {};

  // staging: seg = w*2+c covers LDS bytes [seg*1024, seg*1024+1024); lane offset lane*16
  const int srow = w * 32 + (lane >> 2);     // + c*16
  const int scol = (lane & 3) * 8;
  const _Float16* Abase = A + (size_t)(bm * 128 + srow) * 1024 + scol;
  const _Float16* Bbase = Bt + (size_t)(bn * 128 + srow) * 1024 + scol;

  for (int kt = 0; kt < 32; ++kt) {
    const int k0 = kt * 32;
#pragma unroll
    for (int c = 0; c < 2; ++c) {
      const int seg = w * 2 + c;
      gload_lds16(Abase + (size_t)(c * 16) * 1024 + k0, &Al[seg * 512 + lane * 8]);
      gload_lds16(Bbase + (size_t)(c * 16) * 1024 + k0, &Bl[seg * 512 + lane * 8]);
    }
    __syncthreads();
    h8_t af[4], bf[4];
#pragma unroll
    for (int i = 0; i < 4; ++i)
      af[i] = *reinterpret_cast<const h8_t*>(&Al[(wm * 64 + i * 16 + (lane & 15)) * 32 + (lane >> 4) * 8]);
#pragma unroll
    for (int j = 0; j < 4; ++j)
      bf[j] = *reinterpret_cast<const h8_t*>(&Bl[(wn * 64 + j * 16 + (lane & 15)) * 32 + (lane >> 4) * 8]);
#pragma unroll
    for (int i = 0; i < 4; ++i)
#pragma unroll
      for (int j = 0; j < 4; ++j)
        acc[i][j] = MFMA_16x16x32_F16(af[i], bf[j], acc[i][j]);
    __syncthreads();
  }

  const int gm0 = bm * 128 + wm * 64;
  const int gn0 = bn * 128 + wn * 64;
#pragma unroll
  for (int i = 0; i < 4; ++i) {
#pragma unroll
    for (int j = 0; j < 4; ++j) {
      const int gn = gn0 + j * 16 + (lane & 15);
      const int tm0 = gm0 + i * 16 + (lane >> 4) * 4;  // 4 consecutive rows
      const float bv = bias[gn];
      if (EPI == 0) {
        const int which = gn >> 10;  // 0=Q 1=K 2=V
        const int nn = gn & 1023;
        const int h = nn >> 6, d = nn & 63;
        const int t0 = tm0 & 2047, b = tm0 >> 11;
        const int bh = b * 16 + h;
        if (which == 2) {
          h4_t pack;
#pragma unroll
          for (int r = 0; r < 4; ++r) pack[r] = (_Float16)(acc[i][j][r] + bv);
          *reinterpret_cast<h4_t*>(&outV[((size_t)bh * 64 + d) * 2048 + t0]) = pack;
        } else {
          _Float16* dst = (which == 0) ? outQ : outK;
          const float scale = (which == 0) ? 0.125f : 1.0f;
#pragma unroll
          for (int r = 0; r < 4; ++r)
            dst[((size_t)bh * 2048 + t0 + r) * 64 + d] = (_Float16)((acc[i][j][r] + bv) * scale);
        }
      } else {
#pragma unroll
        for (int r = 0; r < 4; ++r)
          outF[(size_t)(tm0 + r) * 1024 + gn] = acc[i][j][r] + bv;
      }
    }
  }
}

// ---------------- flash attention (causal) ----------------
// Q: (BH,2048,64) f16 pre-scaled by 1/8; K: (BH,2048,64) f16; Vt: (BH,64,2048) f16.
// O: (B*T, 1024) f16. Block = 4 waves, 64 q-rows; KV tiles of 64.
__global__ __launch_bounds__(256, 2) void attn_kernel(
    const _Float16* __restrict__ Q, const _Float16* __restrict__ K,
    const _Float16* __restrict__ Vt, _Float16* __restrict__ O) {
  __shared__ _Float16 Kl[64][72];
  __shared__ _Float16 Vl[64][72];
  __shared__ _Float16 Pl[4][16][72];
  const int tid = threadIdx.x;
  const int lane = tid & 63;
  const int w = tid >> 6;
  const int bh = blockIdx.x >> 5;
  const int qb = blockIdx.x & 31;
  const int b = bh >> 4, h = bh & 15;

  const int qrow = qb * 64 + w * 16 + (lane & 15);
  h8_t qf[2];
#pragma unroll
  for (int kk = 0; kk < 2; ++kk)
    qf[kk] = *reinterpret_cast<const h8_t*>(&Q[((size_t)bh * 2048 + qrow) * 64 + kk * 32 + (lane >> 4) * 8]);

  f32x4 acc[4] = {};
  float mrun[4], lrun[4];
#pragma unroll
  for (int r = 0; r < 4; ++r) { mrun[r] = -1e30f; lrun[r] = 0.f; }

  for (int kt = 0; kt <= qb; ++kt) {
    // stage K tile [64][64] and V^T tile [64(d)][64(t)] into padded LDS
#pragma unroll
    for (int it = 0; it < 2; ++it) {
      const int idx = it * 256 + tid;
      const int row = idx >> 3, c8 = (idx & 7) * 8;
      *reinterpret_cast<h8_t*>(&Kl[row][c8]) =
          *reinterpret_cast<const h8_t*>(&K[((size_t)bh * 2048 + kt * 64 + row) * 64 + c8]);
      *reinterpret_cast<h8_t*>(&Vl[row][c8]) =
          *reinterpret_cast<const h8_t*>(&Vt[((size_t)bh * 64 + row) * 2048 + kt * 64 + c8]);
    }
    __syncthreads();

    // S = Q K^T  (K-dim = D = 64)
    f32x4 s[4] = {};
#pragma unroll
    for (int n = 0; n < 4; ++n)
#pragma unroll
      for (int kk = 0; kk < 2; ++kk) {
        h8_t kf = *reinterpret_cast<const h8_t*>(&Kl[n * 16 + (lane & 15)][kk * 32 + (lane >> 4) * 8]);
        s[n] = MFMA_16x16x32_F16(qf[kk], kf, s[n]);
      }

    if (kt == qb) {  // causal mask on diagonal tile
#pragma unroll
      for (int n = 0; n < 4; ++n) {
        const int col = kt * 64 + n * 16 + (lane & 15);
#pragma unroll
        for (int r = 0; r < 4; ++r) {
          const int row = qb * 64 + w * 16 + (lane >> 4) * 4 + r;
          if (col > row) s[n][r] = -1e30f;
        }
      }
    }

    // online softmax (rows live in 16-lane groups)
    float p[4][4];
#pragma unroll
    for (int r = 0; r < 4; ++r) {
      float mx = fmaxf(fmaxf(s[0][r], s[1][r]), fmaxf(s[2][r], s[3][r]));
      mx = fmaxf(mx, __shfl_xor(mx, 1));
      mx = fmaxf(mx, __shfl_xor(mx, 2));
      mx = fmaxf(mx, __shfl_xor(mx, 4));
      mx = fmaxf(mx, __shfl_xor(mx, 8));
      const float mnew = fmaxf(mrun[r], mx);
      const float al = __expf(mrun[r] - mnew);
      float sum = 0.f;
#pragma unroll
      for (int n = 0; n < 4; ++n) {
        const float pv = __expf(s[n][r] - mnew);
        p[n][r] = pv;
        sum += pv;
      }
      sum += __shfl_xor(sum, 1);
      sum += __shfl_xor(sum, 2);
      sum += __shfl_xor(sum, 4);
      sum += __shfl_xor(sum, 8);
      lrun[r] = lrun[r] * al + sum;
      mrun[r] = mnew;
#pragma unroll
      for (int n = 0; n < 4; ++n) acc[n][r] *= al;
    }

    // P -> LDS (per-wave private), then PV
#pragma unroll
    for (int n = 0; n < 4; ++n)
#pragma unroll
      for (int r = 0; r < 4; ++r)
        Pl[w][(lane >> 4) * 4 + r][n * 16 + (lane & 15)] = (_Float16)p[n][r];
    asm volatile("s_waitcnt lgkmcnt(0)" ::: "memory");

#pragma unroll
    for (int ks = 0; ks < 2; ++ks) {
      h8_t pa = *reinterpret_cast<const h8_t*>(&Pl[w][lane & 15][ks * 32 + (lane >> 4) * 8]);
#pragma unroll
      for (int n = 0; n < 4; ++n) {
        h8_t vf = *reinterpret_cast<const h8_t*>(&Vl[n * 16 + (lane & 15)][ks * 32 + (lane >> 4) * 8]);
        acc[n] = MFMA_16x16x32_F16(pa, vf, acc[n]);
      }
    }
    __syncthreads();
  }

  const int t0 = qb * 64 + w * 16 + (lane >> 4) * 4;
#pragma unroll
  for (int r = 0; r < 4; ++r) {
    const float inv = 1.f / lrun[r];
#pragma unroll
    for (int n = 0; n < 4; ++n)
      O[((size_t)b * 2048 + t0 + r) * 1024 + h * 64 + n * 16 + (lane & 15)] =
          (_Float16)(acc[n][r] * inv);
  }
}

extern "C" void kernel_launch(void* const* d_in, const int* in_sizes, int n_in,
                              void* d_out, int out_size, void* d_ws, size_t ws_size,
                              hipStream_t stream) {
  (void)in_sizes; (void)n_in; (void)out_size; (void)ws_size;
  const float* x = (const float*)d_in[0];
  const float* w_qkv = (const float*)d_in[1];
  const float* b_qkv = (const float*)d_in[2];
  const float* w_out = (const float*)d_in[3];
  const float* b_out = (const float*)d_in[4];
  float* out = (float*)d_out;

  char* ws = (char*)d_ws;
  size_t off = 0;
  auto alloc = [&](size_t bytes) {
    void* p = ws + off;
    off += (bytes + 255) & ~(size_t)255;
    return p;
  };
  _Float16* x16 = (_Float16*)alloc((size_t)8192 * 1024 * 2);
  _Float16* wqkvT = (_Float16*)alloc((size_t)3072 * 1024 * 2);
  _Float16* woutT = (_Float16*)alloc((size_t)1024 * 1024 * 2);
  _Float16* Qh = (_Float16*)alloc((size_t)64 * 2048 * 64 * 2);
  _Float16* Kh = (_Float16*)alloc((size_t)64 * 2048 * 64 * 2);
  _Float16* Vth = (_Float16*)alloc((size_t)64 * 64 * 2048 * 2);
  _Float16* Oh = (_Float16*)alloc((size_t)8192 * 1024 * 2);

  cvt_f16_kernel<<<8192, 256, 0, stream>>>(x, x16, 8192 * 1024 / 4);
  transpose_cvt_kernel<<<dim3(3072 / 32, 1024 / 32), 256, 0, stream>>>(w_qkv, wqkvT, 1024, 3072);
  transpose_cvt_kernel<<<dim3(1024 / 32, 1024 / 32), 256, 0, stream>>>(w_out, woutT, 1024, 1024);
  gemm_bt_kernel<0><<<64 * 24, 256, 0, stream>>>(x16, wqkvT, b_qkv, Qh, Kh, Vth, nullptr, 24);
  attn_kernel<<<64 * 32, 256, 0, stream>>>(Qh, Kh, Vth, Oh);
  gemm_bt_kernel<1><<<64 * 8, 256, 0, stream>>>(Oh, woutT, b_out, nullptr, nullptr, nullptr, out, 8);
}

// Round 3
// 186.476 us; speedup vs baseline: 1.7721x; 1.7721x over previous
//
#include <hip/hip_runtime.h>
#include <cstdint>
#include <cstddef>

typedef _Float16 h8_t __attribute__((ext_vector_type(8)));
typedef _Float16 h4_t __attribute__((ext_vector_type(4)));
typedef float f32x4 __attribute__((ext_vector_type(4)));
typedef float f32x16 __attribute__((ext_vector_type(16)));
typedef unsigned u32x4 __attribute__((ext_vector_type(4)));

#define MFMA_16x16x32_F16(a, b, c) __builtin_amdgcn_mfma_f32_16x16x32_f16(a, b, c, 0, 0, 0)
#define MFMA_32x32x16_F16(a, b, c) __builtin_amdgcn_mfma_f32_32x32x16_f16(a, b, c, 0, 0, 0)

__device__ inline void gload_lds16(const void* g, void* l) {
  __builtin_amdgcn_global_load_lds((const __attribute__((address_space(1))) void*)g,
                                   (__attribute__((address_space(3))) void*)l, 16, 0, 0);
}

// ---------------- convert f32 -> f16 ----------------
__global__ void cvt_f16_kernel(const float* __restrict__ in, _Float16* __restrict__ out, int n4) {
  int i = blockIdx.x * 256 + threadIdx.x;
  if (i >= n4) return;
  float4 v = reinterpret_cast<const float4*>(in)[i];
  h4_t h;
  h[0] = (_Float16)v.x; h[1] = (_Float16)v.y; h[2] = (_Float16)v.z; h[3] = (_Float16)v.w;
  reinterpret_cast<h4_t*>(out)[i] = h;
}

// ---------------- transpose + convert: in[R][Cc] f32 -> out[Cc][R] f16 ----------------
__global__ void transpose_cvt_kernel(const float* __restrict__ in, _Float16* __restrict__ out,
                                     int R, int Cc) {
  __shared__ float tile[32][33];
  int tx = threadIdx.x & 31;
  int ty = threadIdx.x >> 5;  // 0..7
  int c0 = blockIdx.x * 32;
  int r0 = blockIdx.y * 32;
#pragma unroll
  for (int i = 0; i < 4; ++i)
    tile[ty + i * 8][tx] = in[(size_t)(r0 + ty + i * 8) * Cc + (c0 + tx)];
  __syncthreads();
#pragma unroll
  for (int i = 0; i < 4; ++i)
    out[(size_t)(c0 + ty + i * 8) * R + (r0 + tx)] = (_Float16)tile[tx][ty + i * 8];
}

// ---------------- GEMM  C[m][n] = sum_k A[m][k]*Bt[n][k] + bias[n] ----------------
template <int EPI>
__global__ __launch_bounds__(256, 2) void gemm_bt_kernel(
    const _Float16* __restrict__ A, const _Float16* __restrict__ Bt,
    const float* __restrict__ bias, _Float16* __restrict__ outQ,
    _Float16* __restrict__ outK, _Float16* __restrict__ outV,
    float* __restrict__ outF, int NB) {
  __shared__ _Float16 Al[128 * 32];
  __shared__ _Float16 Bl[128 * 32];
  const int tid = threadIdx.x;
  const int lane = tid & 63;
  const int w = tid >> 6;
  const int bm = blockIdx.x / NB;
  const int bn = blockIdx.x % NB;
  const int wm = w & 1, wn = w >> 1;

  f32x4 acc[4][4] = {};

  const int srow = w * 32 + (lane >> 2);
  const int scol = (lane & 3) * 8;
  const _Float16* Abase = A + (size_t)(bm * 128 + srow) * 1024 + scol;
  const _Float16* Bbase = Bt + (size_t)(bn * 128 + srow) * 1024 + scol;

  for (int kt = 0; kt < 32; ++kt) {
    const int k0 = kt * 32;
#pragma unroll
    for (int c = 0; c < 2; ++c) {
      const int seg = w * 2 + c;
      gload_lds16(Abase + (size_t)(c * 16) * 1024 + k0, &Al[seg * 512 + lane * 8]);
      gload_lds16(Bbase + (size_t)(c * 16) * 1024 + k0, &Bl[seg * 512 + lane * 8]);
    }
    __syncthreads();
    h8_t af[4], bf[4];
#pragma unroll
    for (int i = 0; i < 4; ++i)
      af[i] = *reinterpret_cast<const h8_t*>(&Al[(wm * 64 + i * 16 + (lane & 15)) * 32 + (lane >> 4) * 8]);
#pragma unroll
    for (int j = 0; j < 4; ++j)
      bf[j] = *reinterpret_cast<const h8_t*>(&Bl[(wn * 64 + j * 16 + (lane & 15)) * 32 + (lane >> 4) * 8]);
#pragma unroll
    for (int i = 0; i < 4; ++i)
#pragma unroll
      for (int j = 0; j < 4; ++j)
        acc[i][j] = MFMA_16x16x32_F16(af[i], bf[j], acc[i][j]);
    __syncthreads();
  }

  const int gm0 = bm * 128 + wm * 64;
  const int gn0 = bn * 128 + wn * 64;
#pragma unroll
  for (int i = 0; i < 4; ++i) {
#pragma unroll
    for (int j = 0; j < 4; ++j) {
      const int gn = gn0 + j * 16 + (lane & 15);
      const int tm0 = gm0 + i * 16 + (lane >> 4) * 4;
      const float bv = bias[gn];
      if (EPI == 0) {
        const int which = gn >> 10;  // 0=Q 1=K 2=V
        const int nn = gn & 1023;
        const int h = nn >> 6, d = nn & 63;
        const int t0 = tm0 & 2047, b = tm0 >> 11;
        const int bh = b * 16 + h;
        if (which == 2) {
          h4_t pack;
#pragma unroll
          for (int r = 0; r < 4; ++r) pack[r] = (_Float16)(acc[i][j][r] + bv);
          *reinterpret_cast<h4_t*>(&outV[((size_t)bh * 64 + d) * 2048 + t0]) = pack;
        } else {
          _Float16* dst = (which == 0) ? outQ : outK;
          // Q pre-scaled by log2(e)/sqrt(D) so attention can use exp2 directly
          const float scale = (which == 0) ? 0.18033688011112042f : 1.0f;
#pragma unroll
          for (int r = 0; r < 4; ++r)
            dst[((size_t)bh * 2048 + t0 + r) * 64 + d] = (_Float16)((acc[i][j][r] + bv) * scale);
        }
      } else {
#pragma unroll
        for (int r = 0; r < 4; ++r)
          outF[(size_t)(tm0 + r) * 1024 + gn] = acc[i][j][r] + bv;
      }
    }
  }
}

// ---------------- flash attention (causal), swapped-QK in-register softmax ----------------
// Q: (BH,2048,64) f16 pre-scaled by log2e/8; K: (BH,2048,64); Vt: (BH,64,2048).
// Block: 4 waves x 32 q-rows = 128 q-rows per group; each block does paired groups (g, 15-g)
// => uniform 34 KV-tiles/block, 512 blocks.
__device__ inline void stage_kv(const _Float16* __restrict__ Kbh, const _Float16* __restrict__ Vbh,
                                int kt, _Float16* Kd, _Float16* Vd, int w, int lane) {
  const _Float16* Kg = Kbh + (size_t)kt * 64 * 64;
  const _Float16* Vg = Vbh + kt * 64;
#pragma unroll
  for (int c = 0; c < 2; ++c) {
    const int idx = (2 * w + c) * 64 + lane;
    const int row = idx >> 3;
    const int chs = (idx & 7) ^ (row & 7);  // pre-swizzled global source (T2 via m173)
    gload_lds16(Kg + row * 64 + chs * 8, Kd + idx * 8);
    gload_lds16(Vg + (size_t)row * 2048 + chs * 8, Vd + idx * 8);
  }
}

// pack 16 exp'd f32 (one 32x32 S-subtile's worth per lane) into 2 PV B-fragments
__device__ inline void pack_pfrag(const float* e, h8_t* out) {
  unsigned u[8];
#pragma unroll
  for (int i = 0; i < 8; ++i) {
    auto hv = __builtin_amdgcn_cvt_pkrtz(e[2 * i], e[2 * i + 1]);
    u[i] = __builtin_bit_cast(unsigned, hv);
  }
  auto r02 = __builtin_amdgcn_permlane32_swap(u[0], u[2], false, false);
  auto r13 = __builtin_amdgcn_permlane32_swap(u[1], u[3], false, false);
  auto r46 = __builtin_amdgcn_permlane32_swap(u[4], u[6], false, false);
  auto r57 = __builtin_amdgcn_permlane32_swap(u[5], u[7], false, false);
  u32x4 w0 = {(unsigned)r02[0], (unsigned)r13[0], (unsigned)r02[1], (unsigned)r13[1]};
  u32x4 w1 = {(unsigned)r46[0], (unsigned)r57[0], (unsigned)r46[1], (unsigned)r57[1]};
  out[0] = __builtin_bit_cast(h8_t, w0);
  out[1] = __builtin_bit_cast(h8_t, w1);
}

__global__ __launch_bounds__(256, 2) void attn_kernel(
    const _Float16* __restrict__ Q, const _Float16* __restrict__ K,
    const _Float16* __restrict__ Vt, _Float16* __restrict__ O) {
  __shared__ _Float16 Kl[2][64 * 64];
  __shared__ _Float16 Vl[2][64 * 64];
  const int tid = threadIdx.x;
  const int lane = tid & 63;
  const int w = tid >> 6;
  const int hi = lane >> 5;
  const int l31 = lane & 31;
  const int bh = blockIdx.x >> 3;
  const int pr = blockIdx.x & 7;  // pair index 0..7
  const int b = bh >> 4, h = bh & 15;
  const _Float16* Kbh = K + (size_t)bh * 2048 * 64;
  const _Float16* Vbh = Vt + (size_t)bh * 64 * 2048;

#pragma unroll
  for (int gi = 0; gi < 2; ++gi) {
    const int g = gi ? (15 - pr) : pr;
    const int nt = 2 * g + 2;
    const int qbase = g * 128 + w * 32;
    const int qrow = qbase + l31;

    h8_t qf[4];
    const _Float16* Qp = Q + ((size_t)bh * 2048 + qrow) * 64 + hi * 8;
#pragma unroll
    for (int ds = 0; ds < 4; ++ds)
      qf[ds] = *reinterpret_cast<const h8_t*>(Qp + ds * 16);

    f32x16 oa[2] = {};
    float m = -1e30f, lsum = 0.f;

    stage_kv(Kbh, Vbh, 0, &Kl[0][0], &Vl[0][0], w, lane);
    __syncthreads();

    for (int kt = 0; kt < nt; ++kt) {
      const int cur = kt & 1;
      if (kt + 1 < nt)
        stage_kv(Kbh, Vbh, kt + 1, &Kl[cur ^ 1][0], &Vl[cur ^ 1][0], w, lane);

      if (kt * 64 <= qbase + 31) {  // wave not fully above the diagonal
        const char* Kb = (const char*)&Kl[cur][0];
        const char* Vb = (const char*)&Vl[cur][0];
        // S^T = K . Q^T : col = q = l31, rows = k
        f32x16 s0 = {}, s1 = {};
#pragma unroll
        for (int ds = 0; ds < 4; ++ds) {
          const int bc = ds * 32 + hi * 16;
          h8_t kf0 = *(const h8_t*)(Kb + l31 * 128 + (bc ^ ((l31 & 7) << 4)));
          h8_t kf1 = *(const h8_t*)(Kb + (32 + l31) * 128 + (bc ^ ((l31 & 7) << 4)));
          s0 = MFMA_32x32x16_F16(kf0, qf[ds], s0);
          s1 = MFMA_32x32x16_F16(kf1, qf[ds], s1);
        }
        if (kt >= 2 * g) {  // diagonal tiles: mask k > q
#pragma unroll
          for (int r = 0; r < 16; ++r) {
            const int kr = kt * 64 + (r & 3) + 8 * (r >> 2) + 4 * hi;
            if (kr > qrow) s0[r] = -1e30f;
            if (kr + 32 > qrow) s1[r] = -1e30f;
          }
        }
        // row max: 31 in-register fmax + 1 cross-half shuffle
        float t[16];
#pragma unroll
        for (int r = 0; r < 16; ++r) t[r] = fmaxf(s0[r], s1[r]);
#pragma unroll
        for (int st = 8; st >= 1; st >>= 1)
#pragma unroll
          for (int r = 0; r < st; ++r) t[r] = fmaxf(t[r], t[r + st]);
        const float pmax = fmaxf(t[0], __shfl_xor(t[0], 32));
        const float mnew = fmaxf(m, pmax);
        if (__any(mnew > m + 8.f)) {  // defer-max (T13)
          const float al = __builtin_amdgcn_exp2f(m - mnew);
          lsum *= al;
#pragma unroll
          for (int r = 0; r < 16; ++r) { oa[0][r] *= al; oa[1][r] *= al; }
          m = mnew;
        }
        float e0[16], e1[16];
#pragma unroll
        for (int r = 0; r < 16; ++r) {
          e0[r] = __builtin_amdgcn_exp2f(s0[r] - m);
          e1[r] = __builtin_amdgcn_exp2f(s1[r] - m);
        }
        float ps = 0.f;
#pragma unroll
        for (int r = 0; r < 16; ++r) ps += e0[r] + e1[r];
        ps += __shfl_xor(ps, 32);
        lsum += ps;
        // P -> f16 B-fragments fully in-register (T12)
        h8_t pf[4];
        pack_pfrag(e0, pf + 0);
        pack_pfrag(e1, pf + 2);
        // O^T += V^T . P^T  (col = q, rows = d -> rescale is lane-uniform)
#pragma unroll
        for (int dt = 0; dt < 2; ++dt) {
#pragma unroll
          for (int kg = 0; kg < 4; ++kg) {
            const int row = dt * 32 + l31;
            const int bc = kg * 32 + hi * 16;
            h8_t vf = *(const h8_t*)(Vb + row * 128 + (bc ^ ((row & 7) << 4)));
            oa[dt] = MFMA_32x32x16_F16(vf, pf[kg], oa[dt]);
          }
        }
      }
      __syncthreads();
    }

    const float inv = __builtin_amdgcn_rcpf(lsum);
    _Float16* Op = O + ((size_t)b * 2048 + qrow) * 1024 + h * 64;
#pragma unroll
    for (int dt = 0; dt < 2; ++dt) {
#pragma unroll
      for (int rg = 0; rg < 4; ++rg) {
        h4_t pk4;
#pragma unroll
        for (int i = 0; i < 4; ++i) pk4[i] = (_Float16)(oa[dt][rg * 4 + i] * inv);
        *reinterpret_cast<h4_t*>(Op + dt * 32 + rg * 8 + hi * 4) = pk4;
      }
    }
  }
}

extern "C" void kernel_launch(void* const* d_in, const int* in_sizes, int n_in,
                              void* d_out, int out_size, void* d_ws, size_t ws_size,
                              hipStream_t stream) {
  (void)in_sizes; (void)n_in; (void)out_size; (void)ws_size;
  const float* x = (const float*)d_in[0];
  const float* w_qkv = (const float*)d_in[1];
  const float* b_qkv = (const float*)d_in[2];
  const float* w_out = (const float*)d_in[3];
  const float* b_out = (const float*)d_in[4];
  float* out = (float*)d_out;

  char* ws = (char*)d_ws;
  size_t off = 0;
  auto alloc = [&](size_t bytes) {
    void* p = ws + off;
    off += (bytes + 255) & ~(size_t)255;
    return p;
  };
  _Float16* x16 = (_Float16*)alloc((size_t)8192 * 1024 * 2);
  _Float16* wqkvT = (_Float16*)alloc((size_t)3072 * 1024 * 2);
  _Float16* woutT = (_Float16*)alloc((size_t)1024 * 1024 * 2);
  _Float16* Qh = (_Float16*)alloc((size_t)64 * 2048 * 64 * 2);
  _Float16* Kh = (_Float16*)alloc((size_t)64 * 2048 * 64 * 2);
  _Float16* Vth = (_Float16*)alloc((size_t)64 * 64 * 2048 * 2);
  _Float16* Oh = (_Float16*)alloc((size_t)8192 * 1024 * 2);

  cvt_f16_kernel<<<8192, 256, 0, stream>>>(x, x16, 8192 * 1024 / 4);
  transpose_cvt_kernel<<<dim3(3072 / 32, 1024 / 32), 256, 0, stream>>>(w_qkv, wqkvT, 1024, 3072);
  transpose_cvt_kernel<<<dim3(1024 / 32, 1024 / 32), 256, 0, stream>>>(w_out, woutT, 1024, 1024);
  gemm_bt_kernel<0><<<64 * 24, 256, 0, stream>>>(x16, wqkvT, b_qkv, Qh, Kh, Vth, nullptr, 24);
  attn_kernel<<<64 * 8, 256, 0, stream>>>(Qh, Kh, Vth, Oh);
  gemm_bt_kernel<1><<<64 * 8, 256, 0, stream>>>(Oh, woutT, b_out, nullptr, nullptr, nullptr, out, 8);
}